// Round 14
// baseline (889.310 us; speedup 1.0000x reference)
//
#include <hip/hip_runtime.h>
#include <math.h>

#define BN 4
#define HW 1024
#define SP 1024

static constexpr float EPS = 1e-5f;
static constexpr float TEMPF = 3.0f;
static constexpr float MASK_FILL = 1e-4f;
static constexpr size_t CH1 = (size_t)HW * SP;        // 1M floats
static constexpr size_t CH10 = (size_t)10 * HW * SP;  // 10.5M floats

// ---------------- reductions ----------------
__device__ __forceinline__ float wave_max(float v) {
    for (int o = 32; o; o >>= 1) v = fmaxf(v, __shfl_xor(v, o));
    return v;
}
__device__ __forceinline__ float wave_sum(float v) {
    for (int o = 32; o; o >>= 1) v += __shfl_xor(v, o);
    return v;
}
__device__ __forceinline__ float block_max(float v, float* red) {
    v = wave_max(v);
    int w = threadIdx.x >> 6;
    if ((threadIdx.x & 63) == 0) red[w] = v;
    __syncthreads();
    v = fmaxf(fmaxf(red[0], red[1]), fmaxf(red[2], red[3]));
    __syncthreads();
    return v;
}
__device__ __forceinline__ float block_sum(float v, float* red) {
    v = wave_sum(v);
    int w = threadIdx.x >> 6;
    if ((threadIdx.x & 63) == 0) red[w] = v;
    __syncthreads();
    v = red[0] + red[1] + red[2] + red[3];
    __syncthreads();
    return v;
}

// ---------------- weight transpose prep ----------------
// wt layout: L0 @0   [tap][w1:10|w2:10]           (180)
//            L1 @180 [ci][tap][w1:10|w2:10]       (1800)
//            L2 @1980 [ci][tap][w1:1|w2:1]        (180)
__global__ void wt_prep(const float* __restrict__ l0w1, const float* __restrict__ l0w2,
                        const float* __restrict__ l1w1, const float* __restrict__ l1w2,
                        const float* __restrict__ l2w1, const float* __restrict__ l2w2,
                        float* __restrict__ wt) {
    int t = threadIdx.x;
    for (int i = t; i < 90; i += 256) {
        int co = i % 10, tap = i / 10;
        wt[tap * 20 + co] = l0w1[co * 9 + tap];
        wt[tap * 20 + 10 + co] = l0w2[co * 9 + tap];
    }
    for (int i = t; i < 900; i += 256) {
        int co = i % 10, tap = (i / 10) % 9, ci = i / 90;
        wt[180 + ci * 180 + tap * 20 + co] = l1w1[(co * 10 + ci) * 9 + tap];
        wt[180 + ci * 180 + tap * 20 + 10 + co] = l1w2[(co * 10 + ci) * 9 + tap];
    }
    for (int i = t; i < 90; i += 256) {
        int tap = i % 9, ci = i / 9;
        wt[1980 + ci * 18 + tap * 2 + 0] = l2w1[ci * 9 + tap];
        wt[1980 + ci * 18 + tap * 2 + 1] = l2w2[ci * 9 + tap];
    }
}

// ---------------- column max over hw for each sp; batch via blockIdx.y ----------------
template <bool SUM2>
__global__ void colmax_part(const float* __restrict__ in1, const float* __restrict__ in2,
                            float* __restrict__ part) {
    size_t b = blockIdx.y;
    in1 += b * CH1; in2 += b * CH1; part += b * 256 * SP;
    int blk = blockIdx.x;
    int p4 = threadIdx.x << 2;
    size_t base = (size_t)blk * 4 * SP + p4;
    float4 m = {-INFINITY, -INFINITY, -INFINITY, -INFINITY};
#pragma unroll
    for (int r = 0; r < 4; ++r) {
        float4 v = *(const float4*)&in1[base + (size_t)r * SP];
        if (SUM2) {
            float4 u = *(const float4*)&in2[base + (size_t)r * SP];
            v.x += u.x; v.y += u.y; v.z += u.z; v.w += u.w;
        }
        m.x = fmaxf(m.x, v.x); m.y = fmaxf(m.y, v.y);
        m.z = fmaxf(m.z, v.z); m.w = fmaxf(m.w, v.w);
    }
    *(float4*)&part[(size_t)blk * SP + p4] = m;
}

__global__ void colmax_comb(const float* __restrict__ part, float* __restrict__ binv) {
    size_t b = blockIdx.y;
    part += b * 256 * SP; binv += b * SP;
    int col = (blockIdx.x << 8) + threadIdx.x;
    float m = -INFINITY;
    for (int c = 0; c < 256; ++c) m = fmaxf(m, part[(size_t)c * SP + col]);
    binv[col] = 1.0f / (m + EPS);
}

// ---------------- mutual matching (row-max fused); batch via blockIdx.y ----------------
__global__ void mm_rows(const float* __restrict__ in, const float* __restrict__ binv,
                        float* __restrict__ out) {
    size_t b = blockIdx.y;
    in += b * CH1; binv += b * SP; out += b * CH1;
    __shared__ float red[4];
    int row = blockIdx.x;
    int p4 = threadIdx.x << 2;
    float4 v = *(const float4*)&in[(size_t)row * SP + p4];
    float m = fmaxf(fmaxf(v.x, v.y), fmaxf(v.z, v.w));
    m = block_max(m, red);
    float rinv = 1.0f / (m + EPS);
    float4 bi = *(const float4*)&binv[p4];
    float4 o;
    o.x = v.x * v.x * v.x * rinv * bi.x;
    o.y = v.y * v.y * v.y * rinv * bi.y;
    o.z = v.z * v.z * v.z * rinv * bi.z;
    o.w = v.w * v.w * v.w * rinv * bi.w;
    *(float4*)&out[(size_t)row * SP + p4] = o;
}

// ---------------- 4D conv body (round-11 proven; 256 thr x 4 sp, 1 hw) --------
// Used for CI=1 (L0) and CO=1 (L2). Weights from global via aligned dwordx4.
// NOTE: __launch_bounds__(256) size-only; min-waves arg is a VGPR cliff
// (r6: arg=8 -> 32 VGPR; r8: arg=4 -> 64 VGPR; both spill, FETCH x7-14).
// LDS weight staging also regresses (r12: VGPR 108->168, 30ms outlier).
template <int CI, int CO, bool SWAP>
__device__ __forceinline__ void conv_body(const float* __restrict__ in,
                                          float* __restrict__ out,
                                          const float* __restrict__ wt,
                                          const float* __restrict__ bA,
                                          const float* __restrict__ bB,
                                          float (*tile)[SP], int hw) {
    int h = hw >> 5, w = hw & 31;
    int tid = threadIdx.x;
    int p4 = tid << 2;   // 4 consecutive sp, same hs row (ws0 <= 28)
    int ws0 = p4 & 31;
    int hs = p4 >> 5;

    float acc[CO][4];
#pragma unroll
    for (int co = 0; co < CO; ++co) {
        float bsum = bA[co] + bB[co];
#pragma unroll
        for (int k = 0; k < 4; ++k) acc[co][k] = bsum;
    }

    float4 pre = *(const float4*)&in[(size_t)hw * SP + p4];  // ci=0 in-plane
    for (int ci = 0; ci < CI; ++ci) {
        const float* wci = wt + ci * 9 * 2 * CO;
        float* tl = tile[ci & 1];
        *(float4*)&tl[p4] = pre;
        __syncthreads();
        if (ci + 1 < CI)
            pre = *(const float4*)&in[((size_t)(ci + 1) * HW + hw) * SP + p4];
        const float* inc = in + (size_t)ci * HW * SP;
#pragma unroll
        for (int dh = -1; dh <= 1; ++dh) {
            bool hok = (unsigned)(h + dh) < 32u;
            bool v2 = (unsigned)(hs + dh) < 32u;
            int b2 = p4 + dh * 32;
            float4 c4 = {0.f, 0.f, 0.f, 0.f};
            if (v2) c4 = *(const float4*)&tl[b2];
            float lm = (v2 && ws0 > 0) ? tl[b2 - 1] : 0.0f;
            float lp = (v2 && ws0 < 28) ? tl[b2 + 4] : 0.0f;
            float4 l4[3];
            l4[0] = {lm, c4.x, c4.y, c4.z};   // dw=-1
            l4[1] = c4;                        // dw=0
            l4[2] = {c4.y, c4.z, c4.w, lp};   // dw=+1
#pragma unroll
            for (int dwi = 0; dwi < 3; ++dwi) {
                int dw = dwi - 1;
                bool v1 = hok && ((unsigned)(w + dw) < 32u);
                float4 g4 = {0.f, 0.f, 0.f, 0.f};
                if (v1) g4 = *(const float4*)&inc[(size_t)(hw + dh * 32 + dw) * SP + p4];
                int tap = (dh + 1) * 3 + dwi;
                const float* wp = wci + tap * 2 * CO;
                if constexpr (CO == 10) {
                    float4 f0 = *(const float4*)&wp[0];
                    float4 f1 = *(const float4*)&wp[4];
                    float4 f2 = *(const float4*)&wp[8];
                    float4 f3 = *(const float4*)&wp[12];
                    float4 f4 = *(const float4*)&wp[16];
                    float wa[10] = {f0.x, f0.y, f0.z, f0.w, f1.x,
                                    f1.y, f1.z, f1.w, f2.x, f2.y};
                    float wb[10] = {f2.z, f2.w, f3.x, f3.y, f3.z,
                                    f3.w, f4.x, f4.y, f4.z, f4.w};
#pragma unroll
                    for (int co = 0; co < 10; ++co) {
                        float w1v = SWAP ? wb[co] : wa[co];
                        float w2v = SWAP ? wa[co] : wb[co];
                        acc[co][0] = fmaf(g4.x, w1v, fmaf(l4[dwi].x, w2v, acc[co][0]));
                        acc[co][1] = fmaf(g4.y, w1v, fmaf(l4[dwi].y, w2v, acc[co][1]));
                        acc[co][2] = fmaf(g4.z, w1v, fmaf(l4[dwi].z, w2v, acc[co][2]));
                        acc[co][3] = fmaf(g4.w, w1v, fmaf(l4[dwi].w, w2v, acc[co][3]));
                    }
                } else {  // CO == 1
                    float2 f = *(const float2*)&wp[0];
                    float w1v = SWAP ? f.y : f.x;
                    float w2v = SWAP ? f.x : f.y;
                    acc[0][0] = fmaf(g4.x, w1v, fmaf(l4[dwi].x, w2v, acc[0][0]));
                    acc[0][1] = fmaf(g4.y, w1v, fmaf(l4[dwi].y, w2v, acc[0][1]));
                    acc[0][2] = fmaf(g4.z, w1v, fmaf(l4[dwi].z, w2v, acc[0][2]));
                    acc[0][3] = fmaf(g4.w, w1v, fmaf(l4[dwi].w, w2v, acc[0][3]));
                }
            }
        }
        // no loop-end barrier: double buffering makes the post-write barrier
        // of the NEXT iteration sufficient
    }

#pragma unroll
    for (int co = 0; co < CO; ++co) {
        float* op = out + ((size_t)co * HW + hw) * SP + p4;
        float4 r;
        r.x = fmaxf(acc[co][0], 0.0f);
        r.y = fmaxf(acc[co][1], 0.0f);
        r.z = fmaxf(acc[co][2], 0.0f);
        r.w = fmaxf(acc[co][3], 0.0f);
        *(float4*)op = r;
    }
}

template <int CI, int CO>
__global__ __launch_bounds__(256) void conv4d(
    const float* __restrict__ in0, const float* __restrict__ in1,
    float* __restrict__ out0, float* __restrict__ out1,
    const float* __restrict__ wt,
    const float* __restrict__ bA, const float* __restrict__ bB,
    int branch_base) {
    __shared__ float tile[2][SP];
    int branch = blockIdx.y + branch_base;
    int hw = blockIdx.x;
    if (branch == 0)
        conv_body<CI, CO, false>(in0, out0, wt, bA, bB, tile, hw);
    else
        conv_body<CI, CO, true>(in1, out1, wt, bA, bB, tile, hw);
}

// ---------------- L1 conv: one ci of the pair body ----------------
template <bool SWAP>
__device__ __forceinline__ void conv_pair_ci(const float* __restrict__ inc,
                                             const float* __restrict__ wci,
                                             const float* tlA, const float* tlB,
                                             float (&acc0)[10][4], float (&acc1)[10][4],
                                             int h, int w0, int hw0,
                                             int p4, int ws0, int hs) {
#pragma unroll
    for (int dh = -1; dh <= 1; ++dh) {
        bool hok = (unsigned)(h + dh) < 32u;
        bool v2 = (unsigned)(hs + dh) < 32u;
        int b2 = p4 + dh * 32;
        float4 cA = {0.f, 0.f, 0.f, 0.f}, cB = {0.f, 0.f, 0.f, 0.f};
        float lmA = 0.f, lpA = 0.f, lmB = 0.f, lpB = 0.f;
        if (v2) {
            cA = *(const float4*)&tlA[b2];
            cB = *(const float4*)&tlB[b2];
            if (ws0 > 0) { lmA = tlA[b2 - 1]; lmB = tlB[b2 - 1]; }
            if (ws0 < 28) { lpA = tlA[b2 + 4]; lpB = tlB[b2 + 4]; }
        }
        float4 lA[3], lB[3];
        lA[0] = {lmA, cA.x, cA.y, cA.z}; lA[1] = cA; lA[2] = {cA.y, cA.z, cA.w, lpA};
        lB[0] = {lmB, cB.x, cB.y, cB.z}; lB[1] = cB; lB[2] = {cB.y, cB.z, cB.w, lpB};
        // g-planes for columns w0-1 .. w0+2 (serve both centers)
        float4 g[4];
#pragma unroll
        for (int dc = 0; dc < 4; ++dc) {
            bool ok = hok && ((unsigned)(w0 + dc - 1) < 32u);
            g[dc] = {0.f, 0.f, 0.f, 0.f};
            if (ok) g[dc] = *(const float4*)&inc[(size_t)(hw0 + dh * 32 + dc - 1) * SP + p4];
        }
#pragma unroll
        for (int dwi = 0; dwi < 3; ++dwi) {
            int tap = (dh + 1) * 3 + dwi;
            const float* wp = wci + tap * 20;
            float4 f0 = *(const float4*)&wp[0];
            float4 f1 = *(const float4*)&wp[4];
            float4 f2 = *(const float4*)&wp[8];
            float4 f3 = *(const float4*)&wp[12];
            float4 f4 = *(const float4*)&wp[16];
            float wa[10] = {f0.x, f0.y, f0.z, f0.w, f1.x,
                            f1.y, f1.z, f1.w, f2.x, f2.y};
            float wb[10] = {f2.z, f2.w, f3.x, f3.y, f3.z,
                            f3.w, f4.x, f4.y, f4.z, f4.w};
#pragma unroll
            for (int co = 0; co < 10; ++co) {
                float w1v = SWAP ? wb[co] : wa[co];
                float w2v = SWAP ? wa[co] : wb[co];
                acc0[co][0] = fmaf(g[dwi].x, w1v, fmaf(lA[dwi].x, w2v, acc0[co][0]));
                acc0[co][1] = fmaf(g[dwi].y, w1v, fmaf(lA[dwi].y, w2v, acc0[co][1]));
                acc0[co][2] = fmaf(g[dwi].z, w1v, fmaf(lA[dwi].z, w2v, acc0[co][2]));
                acc0[co][3] = fmaf(g[dwi].w, w1v, fmaf(lA[dwi].w, w2v, acc0[co][3]));
                acc1[co][0] = fmaf(g[dwi + 1].x, w1v, fmaf(lB[dwi].x, w2v, acc1[co][0]));
                acc1[co][1] = fmaf(g[dwi + 1].y, w1v, fmaf(lB[dwi].y, w2v, acc1[co][1]));
                acc1[co][2] = fmaf(g[dwi + 1].z, w1v, fmaf(lB[dwi].z, w2v, acc1[co][2]));
                acc1[co][3] = fmaf(g[dwi + 1].w, w1v, fmaf(lB[dwi].w, w2v, acc1[co][3]));
            }
        }
    }
}

// ---------------- L1 conv: 2 adjacent hw columns/thread, 5-plane staging -----
// Staging 5 ci-planes per barrier widens the vmcnt-drain window 3.3x (the
// compiler emits s_waitcnt vmcnt(0) before every s_barrier; per-ci staging
// drained all in-flight g-loads every ~1080 FMAs -> 35% stall, r11/r13).
// 3 barriers total; LDS 40KB single-buffered (still 4 blocks/CU, same as the
// VGPR-limited residency). Weights from global dwordx4 (r12's LDS staging
// regressed: VGPR 108->168).
template <bool SWAP>
__device__ __forceinline__ void conv_pair_body(const float* __restrict__ in,
                                               float* __restrict__ out,
                                               const float* __restrict__ wt,
                                               const float* __restrict__ bA,
                                               const float* __restrict__ bB,
                                               float (*tile)[2][SP], int h, int w0) {
    int tid = threadIdx.x;
    int p4 = tid << 2;
    int ws0 = p4 & 31;
    int hs = p4 >> 5;
    int hw0 = h * 32 + w0;

    float acc0[10][4], acc1[10][4];
#pragma unroll
    for (int co = 0; co < 10; ++co) {
        float bsum = bA[co] + bB[co];
#pragma unroll
        for (int k = 0; k < 4; ++k) { acc0[co][k] = bsum; acc1[co][k] = bsum; }
    }

    // stage planes 0..4
#pragma unroll
    for (int r = 0; r < 5; ++r) {
        float4 a = *(const float4*)&in[((size_t)r * HW + hw0) * SP + p4];
        float4 b = *(const float4*)&in[((size_t)r * HW + hw0 + 1) * SP + p4];
        *(float4*)&tile[r][0][p4] = a;
        *(float4*)&tile[r][1][p4] = b;
    }
    __syncthreads();

    for (int ci = 0; ci < 5; ++ci)
        conv_pair_ci<SWAP>(in + (size_t)ci * HW * SP, wt + ci * 180,
                           tile[ci][0], tile[ci][1], acc0, acc1,
                           h, w0, hw0, p4, ws0, hs);

    __syncthreads();   // stage-0 reads complete before overwrite

    // stage planes 5..9
#pragma unroll
    for (int r = 0; r < 5; ++r) {
        float4 a = *(const float4*)&in[((size_t)(5 + r) * HW + hw0) * SP + p4];
        float4 b = *(const float4*)&in[((size_t)(5 + r) * HW + hw0 + 1) * SP + p4];
        *(float4*)&tile[r][0][p4] = a;
        *(float4*)&tile[r][1][p4] = b;
    }
    __syncthreads();

    for (int ci = 5; ci < 10; ++ci)
        conv_pair_ci<SWAP>(in + (size_t)ci * HW * SP, wt + ci * 180,
                           tile[ci - 5][0], tile[ci - 5][1], acc0, acc1,
                           h, w0, hw0, p4, ws0, hs);

#pragma unroll
    for (int co = 0; co < 10; ++co) {
        float* op0 = out + ((size_t)co * HW + hw0) * SP + p4;
        float* op1 = op0 + SP;
        float4 r0, r1;
        r0.x = fmaxf(acc0[co][0], 0.0f); r0.y = fmaxf(acc0[co][1], 0.0f);
        r0.z = fmaxf(acc0[co][2], 0.0f); r0.w = fmaxf(acc0[co][3], 0.0f);
        r1.x = fmaxf(acc1[co][0], 0.0f); r1.y = fmaxf(acc1[co][1], 0.0f);
        r1.z = fmaxf(acc1[co][2], 0.0f); r1.w = fmaxf(acc1[co][3], 0.0f);
        *(float4*)op0 = r0;
        *(float4*)op1 = r1;
    }
}

__global__ __launch_bounds__(256) void conv4d_pair(
    const float* __restrict__ in0, const float* __restrict__ in1,
    float* __restrict__ out0, float* __restrict__ out1,
    const float* __restrict__ wt,
    const float* __restrict__ bA, const float* __restrict__ bB,
    int branch_base) {
    __shared__ float tile[5][2][SP];   // 40 KB, single-buffered
    int branch = blockIdx.y + branch_base;
    int bx = blockIdx.x;           // 512 blocks: h in [0,32), w-pair in [0,16)
    int h = bx >> 4;
    int w0 = (bx & 15) << 1;
    if (branch == 0)
        conv_pair_body<false>(in0, out0, wt, bA, bB, tile, h, w0);
    else
        conv_pair_body<true>(in1, out1, wt, bA, bB, tile, h, w0);
}

// ---------------- mm + mask + softmax, s = s1+s2; batch via blockIdx.y ----------------
__global__ void mm_softmax(const float* __restrict__ s1, const float* __restrict__ s2,
                           const float* __restrict__ binv, const int* __restrict__ mask,
                           float* __restrict__ attn) {
    size_t b = blockIdx.y;
    s1 += b * CH1; s2 += b * CH1; binv += b * SP; mask += b * SP; attn += b * CH1;
    __shared__ float red[4];
    int row = blockIdx.x;
    int p4 = threadIdx.x << 2;
    float4 v = *(const float4*)&s1[(size_t)row * SP + p4];
    float4 u = *(const float4*)&s2[(size_t)row * SP + p4];
    v.x += u.x; v.y += u.y; v.z += u.z; v.w += u.w;
    float m = fmaxf(fmaxf(v.x, v.y), fmaxf(v.z, v.w));
    m = block_max(m, red);
    float rinv = 1.0f / (m + EPS);
    float4 bi = *(const float4*)&binv[p4];
    int4 mk = *(const int4*)&mask[p4];
    float lg[4];
    lg[0] = (mk.x != 0) ? MASK_FILL * TEMPF : v.x * v.x * v.x * rinv * bi.x * TEMPF;
    lg[1] = (mk.y != 0) ? MASK_FILL * TEMPF : v.y * v.y * v.y * rinv * bi.y * TEMPF;
    lg[2] = (mk.z != 0) ? MASK_FILL * TEMPF : v.z * v.z * v.z * rinv * bi.z * TEMPF;
    lg[3] = (mk.w != 0) ? MASK_FILL * TEMPF : v.w * v.w * v.w * rinv * bi.w * TEMPF;
    float lm = fmaxf(fmaxf(lg[0], lg[1]), fmaxf(lg[2], lg[3]));
    lm = block_max(lm, red);
    float e[4], ss = 0.0f;
#pragma unroll
    for (int k = 0; k < 4; ++k) {
        e[k] = expf(lg[k] - lm);
        ss += e[k];
    }
    ss = block_sum(ss, red);
    float inv = 1.0f / ss;
    float4 o = {e[0] * inv, e[1] * inv, e[2] * inv, e[3] * inv};
    *(float4*)&attn[(size_t)row * SP + p4] = o;
}

// ---------------- einsum GEMM: out[c,q] = sum_s V[c,s]*A[q,s]; batch via blockIdx.z ----------------
__global__ __launch_bounds__(256) void gemm_vat(const float* __restrict__ V,
                                                const float* __restrict__ A,
                                                float* __restrict__ out) {
    size_t b = blockIdx.z;
    V += b * 256 * 1024; A += b * CH1; out += b * 256 * 1024;
    __shared__ float As[64][36];
    __shared__ float Bs[64][36];
    int c0 = blockIdx.y * 64, q0 = blockIdx.x * 64;
    int tr = threadIdx.x & 15, tc = threadIdx.x >> 4;
    float acc[4][4] = {};
    for (int k0 = 0; k0 < 1024; k0 += 32) {
#pragma unroll
        for (int j = 0; j < 2; ++j) {
            int idx = threadIdx.x + j * 256;
            int row = idx >> 3, c4 = (idx & 7) * 4;
            *(float4*)&As[row][c4] = *(const float4*)&V[(size_t)(c0 + row) * 1024 + k0 + c4];
            *(float4*)&Bs[row][c4] = *(const float4*)&A[(size_t)(q0 + row) * 1024 + k0 + c4];
        }
        __syncthreads();
#pragma unroll
        for (int kk = 0; kk < 8; ++kk) {
            float4 a[4], bb[4];
#pragma unroll
            for (int i = 0; i < 4; ++i) a[i] = *(float4*)&As[tr * 4 + i][kk * 4];
#pragma unroll
            for (int j = 0; j < 4; ++j) bb[j] = *(float4*)&Bs[tc * 4 + j][kk * 4];
#pragma unroll
            for (int i = 0; i < 4; ++i)
#pragma unroll
                for (int j = 0; j < 4; ++j)
                    acc[i][j] += a[i].x * bb[j].x + a[i].y * bb[j].y +
                                 a[i].z * bb[j].z + a[i].w * bb[j].w;
        }
        __syncthreads();
    }
#pragma unroll
    for (int i = 0; i < 4; ++i) {
        float4 o = {acc[i][0], acc[i][1], acc[i][2], acc[i][3]};
        *(float4*)&out[(size_t)(c0 + tr * 4 + i) * 1024 + q0 + tc * 4] = o;
    }
}

extern "C" void kernel_launch(void* const* d_in, const int* in_sizes, int n_in,
                              void* d_out, int out_size, void* d_ws, size_t ws_size,
                              hipStream_t stream) {
    const float* corr = (const float*)d_in[0];
    const float* v = (const float*)d_in[1];
    const int* mask = (const int*)d_in[2];
    const float* l0w1 = (const float*)d_in[3];
    const float* l0b1 = (const float*)d_in[4];
    const float* l0w2 = (const float*)d_in[5];
    const float* l0b2 = (const float*)d_in[6];
    const float* l1w1 = (const float*)d_in[7];
    const float* l1b1 = (const float*)d_in[8];
    const float* l1w2 = (const float*)d_in[9];
    const float* l1b2 = (const float*)d_in[10];
    const float* l2w1 = (const float*)d_in[11];
    const float* l2b1 = (const float*)d_in[12];
    const float* l2w2 = (const float*)d_in[13];
    const float* l2b2 = (const float*)d_in[14];
    float* W = (float*)d_ws;
    float* out = (float*)d_out;
    (void)in_sizes; (void)n_in; (void)out_size;

    const size_t need2 = (4 * CH10 + 12 * CH1 + 2160) * sizeof(float);  // ~218 MB
    const size_t need1 = (4 * CH10 + 2 * CH1 + 2160) * sizeof(float);   // ~176 MB
    dim3 g2(HW, 2), g1(HW, 1);
    dim3 gp2(512, 2), gp1(512, 1);

    if (ws_size >= need2) {
        // -------- fully batched small kernels, branch-parallel convs --------
        float* P1 = W;
        float* Q1 = P1 + CH10;
        float* P2 = Q1 + CH10;
        float* Q2 = P2 + CH10;
        float* C1 = Q2 + CH10;            // 4 x CH1
        float* S = C1 + 4 * CH1;          // 8 x CH1: S1[b]=S+b*CH1, S2[b]=S+(4+b)*CH1
        float* wt = S + 8 * CH1;
        float* PART = P2;                 // alias: P2 dead during stage1/stage2
        float* MB0 = P2 + 4 * 256 * SP;
        float* MB1 = MB0 + 4 * SP;
        float* ATTN = P1;                 // alias: P1 dead during stage2

        wt_prep<<<1, 256, 0, stream>>>(l0w1, l0w2, l1w1, l1w2, l2w1, l2w2, wt);

        // stage 1, all batches
        colmax_part<false><<<dim3(256, BN), 256, 0, stream>>>(corr, corr, PART);
        colmax_comb<<<dim3(4, BN), 256, 0, stream>>>(PART, MB0);
        mm_rows<<<dim3(HW, BN), 256, 0, stream>>>(corr, MB0, C1);

        // convs per batch (shared P/Q), both branches concurrent
        for (int b = 0; b < BN; ++b) {
            float* C1b = C1 + (size_t)b * CH1;
            float* S1b = S + (size_t)b * CH1;
            float* S2b = S + (size_t)(4 + b) * CH1;
            conv4d<1, 10><<<g2, 256, 0, stream>>>(C1b, C1b, P1, P2, wt, l0b1, l0b2, 0);
            conv4d_pair<<<gp2, 256, 0, stream>>>(P1, P2, Q1, Q2, wt + 180, l1b1, l1b2, 0);
            conv4d<10, 1><<<g2, 256, 0, stream>>>(Q1, Q2, S1b, S2b, wt + 1980, l2b1, l2b2, 0);
        }

        // stage 2, all batches
        colmax_part<true><<<dim3(256, BN), 256, 0, stream>>>(S, S + 4 * CH1, PART);
        colmax_comb<<<dim3(4, BN), 256, 0, stream>>>(PART, MB1);
        mm_softmax<<<dim3(HW, BN), 256, 0, stream>>>(S, S + 4 * CH1, MB1, mask, ATTN);
        gemm_vat<<<dim3(16, 4, BN), 256, 0, stream>>>(v, ATTN, out);
    } else {
        bool par = ws_size >= need1;
        float *P1, *Q1, *P2, *Q2, *C1, *S1, *S2, *wt;
        if (par) {
            P1 = W; Q1 = P1 + CH10; P2 = Q1 + CH10; Q2 = P2 + CH10;
            S1 = Q2 + CH10; S2 = S1 + CH1; wt = S2 + CH1;
            C1 = Q1;
        } else {
            P1 = W; Q1 = P1 + CH10; C1 = Q1 + CH10; S1 = C1 + CH1; S2 = S1 + CH1;
            wt = S2 + CH1;
            P2 = P1; Q2 = Q1;
        }
        float* PART = P1;
        float* MB0 = P1 + 256 * SP;
        float* MB1 = MB0 + SP;
        float* ATTN = P1 + 512 * SP;

        wt_prep<<<1, 256, 0, stream>>>(l0w1, l0w2, l1w1, l1w2, l2w1, l2w2, wt);

        for (int b = 0; b < BN; ++b) {
            const float* corr_b = corr + (size_t)b * CH1;
            const float* v_b = v + (size_t)b * 256 * 1024;
            const int* mask_b = mask + (size_t)b * SP;
            float* out_b = out + (size_t)b * 256 * 1024;

            colmax_part<false><<<dim3(256, 1), 256, 0, stream>>>(corr_b, corr_b, PART);
            colmax_comb<<<dim3(4, 1), 256, 0, stream>>>(PART, MB0);
            mm_rows<<<dim3(HW, 1), 256, 0, stream>>>(corr_b, MB0, C1);

            if (par) {
                conv4d<1, 10><<<g2, 256, 0, stream>>>(C1, C1, P1, P2, wt, l0b1, l0b2, 0);
                conv4d_pair<<<gp2, 256, 0, stream>>>(P1, P2, Q1, Q2, wt + 180, l1b1, l1b2, 0);
                conv4d<10, 1><<<g2, 256, 0, stream>>>(Q1, Q2, S1, S2, wt + 1980, l2b1, l2b2, 0);
            } else {
                conv4d<1, 10><<<g1, 256, 0, stream>>>(C1, C1, P1, P1, wt, l0b1, l0b2, 0);
                conv4d_pair<<<gp1, 256, 0, stream>>>(P1, P1, Q1, Q1, wt + 180, l1b1, l1b2, 0);
                conv4d<10, 1><<<g1, 256, 0, stream>>>(Q1, Q1, S1, S1, wt + 1980, l2b1, l2b2, 0);
                conv4d<1, 10><<<g1, 256, 0, stream>>>(C1, C1, P1, P1, wt, l0b1, l0b2, 1);
                conv4d_pair<<<gp1, 256, 0, stream>>>(P1, P1, Q1, Q1, wt + 180, l1b1, l1b2, 1);
                conv4d<10, 1><<<g1, 256, 0, stream>>>(Q1, Q1, S2, S2, wt + 1980, l2b1, l2b2, 1);
            }

            colmax_part<true><<<dim3(256, 1), 256, 0, stream>>>(S1, S2, PART);
            colmax_comb<<<dim3(4, 1), 256, 0, stream>>>(PART, MB1);
            mm_softmax<<<dim3(HW, 1), 256, 0, stream>>>(S1, S2, MB1, mask_b, ATTN);
            gemm_vat<<<dim3(16, 4, 1), 256, 0, stream>>>(v_b, ATTN, out_b);
        }
    }
}

// Round 15
// 835.968 us; speedup vs baseline: 1.0638x; 1.0638x over previous
//
#include <hip/hip_runtime.h>
#include <math.h>

#define BN 4
#define HW 1024
#define SP 1024

static constexpr float EPS = 1e-5f;
static constexpr float TEMPF = 3.0f;
static constexpr float MASK_FILL = 1e-4f;
static constexpr size_t CH1 = (size_t)HW * SP;        // 1M floats
static constexpr size_t CH10 = (size_t)10 * HW * SP;  // 10.5M floats

// ---------------- reductions ----------------
__device__ __forceinline__ float wave_max(float v) {
    for (int o = 32; o; o >>= 1) v = fmaxf(v, __shfl_xor(v, o));
    return v;
}
__device__ __forceinline__ float wave_sum(float v) {
    for (int o = 32; o; o >>= 1) v += __shfl_xor(v, o);
    return v;
}
__device__ __forceinline__ float block_max(float v, float* red) {
    v = wave_max(v);
    int w = threadIdx.x >> 6;
    if ((threadIdx.x & 63) == 0) red[w] = v;
    __syncthreads();
    v = fmaxf(fmaxf(red[0], red[1]), fmaxf(red[2], red[3]));
    __syncthreads();
    return v;
}
__device__ __forceinline__ float block_sum(float v, float* red) {
    v = wave_sum(v);
    int w = threadIdx.x >> 6;
    if ((threadIdx.x & 63) == 0) red[w] = v;
    __syncthreads();
    v = red[0] + red[1] + red[2] + red[3];
    __syncthreads();
    return v;
}

// ---------------- weight transpose prep ----------------
// wt layout: L0 @0   [tap][w1:10|w2:10]           (180)
//            L1 @180 [ci][tap][w1:10|w2:10]       (1800)
//            L2 @1980 [ci][tap][w1:1|w2:1]        (180)
__global__ void wt_prep(const float* __restrict__ l0w1, const float* __restrict__ l0w2,
                        const float* __restrict__ l1w1, const float* __restrict__ l1w2,
                        const float* __restrict__ l2w1, const float* __restrict__ l2w2,
                        float* __restrict__ wt) {
    int t = threadIdx.x;
    for (int i = t; i < 90; i += 256) {
        int co = i % 10, tap = i / 10;
        wt[tap * 20 + co] = l0w1[co * 9 + tap];
        wt[tap * 20 + 10 + co] = l0w2[co * 9 + tap];
    }
    for (int i = t; i < 900; i += 256) {
        int co = i % 10, tap = (i / 10) % 9, ci = i / 90;
        wt[180 + ci * 180 + tap * 20 + co] = l1w1[(co * 10 + ci) * 9 + tap];
        wt[180 + ci * 180 + tap * 20 + 10 + co] = l1w2[(co * 10 + ci) * 9 + tap];
    }
    for (int i = t; i < 90; i += 256) {
        int tap = i % 9, ci = i / 9;
        wt[1980 + ci * 18 + tap * 2 + 0] = l2w1[ci * 9 + tap];
        wt[1980 + ci * 18 + tap * 2 + 1] = l2w2[ci * 9 + tap];
    }
}

// ---------------- column max over hw for each sp; batch via blockIdx.y ----------------
template <bool SUM2>
__global__ void colmax_part(const float* __restrict__ in1, const float* __restrict__ in2,
                            float* __restrict__ part) {
    size_t b = blockIdx.y;
    in1 += b * CH1; in2 += b * CH1; part += b * 256 * SP;
    int blk = blockIdx.x;
    int p4 = threadIdx.x << 2;
    size_t base = (size_t)blk * 4 * SP + p4;
    float4 m = {-INFINITY, -INFINITY, -INFINITY, -INFINITY};
#pragma unroll
    for (int r = 0; r < 4; ++r) {
        float4 v = *(const float4*)&in1[base + (size_t)r * SP];
        if (SUM2) {
            float4 u = *(const float4*)&in2[base + (size_t)r * SP];
            v.x += u.x; v.y += u.y; v.z += u.z; v.w += u.w;
        }
        m.x = fmaxf(m.x, v.x); m.y = fmaxf(m.y, v.y);
        m.z = fmaxf(m.z, v.z); m.w = fmaxf(m.w, v.w);
    }
    *(float4*)&part[(size_t)blk * SP + p4] = m;
}

__global__ void colmax_comb(const float* __restrict__ part, float* __restrict__ binv) {
    size_t b = blockIdx.y;
    part += b * 256 * SP; binv += b * SP;
    int col = (blockIdx.x << 8) + threadIdx.x;
    float m = -INFINITY;
    for (int c = 0; c < 256; ++c) m = fmaxf(m, part[(size_t)c * SP + col]);
    binv[col] = 1.0f / (m + EPS);
}

// ---------------- mutual matching (row-max fused); batch via blockIdx.y ----------------
__global__ void mm_rows(const float* __restrict__ in, const float* __restrict__ binv,
                        float* __restrict__ out) {
    size_t b = blockIdx.y;
    in += b * CH1; binv += b * SP; out += b * CH1;
    __shared__ float red[4];
    int row = blockIdx.x;
    int p4 = threadIdx.x << 2;
    float4 v = *(const float4*)&in[(size_t)row * SP + p4];
    float m = fmaxf(fmaxf(v.x, v.y), fmaxf(v.z, v.w));
    m = block_max(m, red);
    float rinv = 1.0f / (m + EPS);
    float4 bi = *(const float4*)&binv[p4];
    float4 o;
    o.x = v.x * v.x * v.x * rinv * bi.x;
    o.y = v.y * v.y * v.y * rinv * bi.y;
    o.z = v.z * v.z * v.z * rinv * bi.z;
    o.w = v.w * v.w * v.w * rinv * bi.w;
    *(float4*)&out[(size_t)row * SP + p4] = o;
}

// ---------------- unified conv: 2 adjacent hw columns per thread --------------
// out[co,hw,sp] = relu( bA[co]+bB[co]
//   + sum_ci,tap in[ci,hw+taphw,sp]*whw[..]   (neighbor planes, global/L2)
//   + sum_ci,tap in[ci,hw,sp+tapsp]*wsp[..] ) (in-plane shifts, LDS staged)
// Pair structure (r11's proven win): tap weights shared by both centers,
// hw-neighbor g-planes overlap (4 loads serve 2x3 taps per dh). Weights from
// global dwordx4 (r12's LDS staging regressed: VGPR 108->168). One barrier
// per ci (double-buffered tiles). NOTE: __launch_bounds__(256) size-only;
// the min-waves arg is a VGPR cliff (r6: arg=8 -> 32 VGPR; r8: arg=4 -> 64;
// both spill acc -> FETCH x7-14, 4-8x slower).
template <int CI, int CO, bool SWAP>
__device__ __forceinline__ void conv_pair_body(const float* __restrict__ in,
                                               float* __restrict__ out,
                                               const float* __restrict__ wt,
                                               const float* __restrict__ bA,
                                               const float* __restrict__ bB,
                                               float (*tile)[2][SP], int h, int w0) {
    int tid = threadIdx.x;
    int p4 = tid << 2;
    int ws0 = p4 & 31;
    int hs = p4 >> 5;
    int hw0 = h * 32 + w0;

    float acc0[CO][4], acc1[CO][4];
#pragma unroll
    for (int co = 0; co < CO; ++co) {
        float bsum = bA[co] + bB[co];
#pragma unroll
        for (int k = 0; k < 4; ++k) { acc0[co][k] = bsum; acc1[co][k] = bsum; }
    }

    float4 preA = *(const float4*)&in[(size_t)hw0 * SP + p4];
    float4 preB = *(const float4*)&in[(size_t)(hw0 + 1) * SP + p4];
    for (int ci = 0; ci < CI; ++ci) {
        const float* wci = wt + ci * 9 * 2 * CO;
        float* tlA = tile[ci & 1][0];
        float* tlB = tile[ci & 1][1];
        *(float4*)&tlA[p4] = preA;
        *(float4*)&tlB[p4] = preB;
        __syncthreads();
        if (ci + 1 < CI) {
            preA = *(const float4*)&in[((size_t)(ci + 1) * HW + hw0) * SP + p4];
            preB = *(const float4*)&in[((size_t)(ci + 1) * HW + hw0 + 1) * SP + p4];
        }
        const float* inc = in + (size_t)ci * HW * SP;
#pragma unroll
        for (int dh = -1; dh <= 1; ++dh) {
            bool hok = (unsigned)(h + dh) < 32u;
            bool v2 = (unsigned)(hs + dh) < 32u;
            int b2 = p4 + dh * 32;
            float4 cA = {0.f, 0.f, 0.f, 0.f}, cB = {0.f, 0.f, 0.f, 0.f};
            float lmA = 0.f, lpA = 0.f, lmB = 0.f, lpB = 0.f;
            if (v2) {
                cA = *(const float4*)&tlA[b2];
                cB = *(const float4*)&tlB[b2];
                if (ws0 > 0) { lmA = tlA[b2 - 1]; lmB = tlB[b2 - 1]; }
                if (ws0 < 28) { lpA = tlA[b2 + 4]; lpB = tlB[b2 + 4]; }
            }
            float4 lA[3], lB[3];
            lA[0] = {lmA, cA.x, cA.y, cA.z}; lA[1] = cA; lA[2] = {cA.y, cA.z, cA.w, lpA};
            lB[0] = {lmB, cB.x, cB.y, cB.z}; lB[1] = cB; lB[2] = {cB.y, cB.z, cB.w, lpB};
            // g-planes for columns w0-1 .. w0+2 (serve both centers)
            float4 g[4];
#pragma unroll
            for (int dc = 0; dc < 4; ++dc) {
                bool ok = hok && ((unsigned)(w0 + dc - 1) < 32u);
                g[dc] = {0.f, 0.f, 0.f, 0.f};
                if (ok) g[dc] = *(const float4*)&inc[(size_t)(hw0 + dh * 32 + dc - 1) * SP + p4];
            }
#pragma unroll
            for (int dwi = 0; dwi < 3; ++dwi) {
                int tap = (dh + 1) * 3 + dwi;
                const float* wp = wci + tap * 2 * CO;
                if constexpr (CO == 10) {
                    float4 f0 = *(const float4*)&wp[0];
                    float4 f1 = *(const float4*)&wp[4];
                    float4 f2 = *(const float4*)&wp[8];
                    float4 f3 = *(const float4*)&wp[12];
                    float4 f4 = *(const float4*)&wp[16];
                    float wa[10] = {f0.x, f0.y, f0.z, f0.w, f1.x,
                                    f1.y, f1.z, f1.w, f2.x, f2.y};
                    float wb[10] = {f2.z, f2.w, f3.x, f3.y, f3.z,
                                    f3.w, f4.x, f4.y, f4.z, f4.w};
#pragma unroll
                    for (int co = 0; co < 10; ++co) {
                        float w1v = SWAP ? wb[co] : wa[co];
                        float w2v = SWAP ? wa[co] : wb[co];
                        acc0[co][0] = fmaf(g[dwi].x, w1v, fmaf(lA[dwi].x, w2v, acc0[co][0]));
                        acc0[co][1] = fmaf(g[dwi].y, w1v, fmaf(lA[dwi].y, w2v, acc0[co][1]));
                        acc0[co][2] = fmaf(g[dwi].z, w1v, fmaf(lA[dwi].z, w2v, acc0[co][2]));
                        acc0[co][3] = fmaf(g[dwi].w, w1v, fmaf(lA[dwi].w, w2v, acc0[co][3]));
                        acc1[co][0] = fmaf(g[dwi + 1].x, w1v, fmaf(lB[dwi].x, w2v, acc1[co][0]));
                        acc1[co][1] = fmaf(g[dwi + 1].y, w1v, fmaf(lB[dwi].y, w2v, acc1[co][1]));
                        acc1[co][2] = fmaf(g[dwi + 1].z, w1v, fmaf(lB[dwi].z, w2v, acc1[co][2]));
                        acc1[co][3] = fmaf(g[dwi + 1].w, w1v, fmaf(lB[dwi].w, w2v, acc1[co][3]));
                    }
                } else {  // CO == 1
                    float2 f = *(const float2*)&wp[0];
                    float w1v = SWAP ? f.y : f.x;
                    float w2v = SWAP ? f.x : f.y;
                    acc0[0][0] = fmaf(g[dwi].x, w1v, fmaf(lA[dwi].x, w2v, acc0[0][0]));
                    acc0[0][1] = fmaf(g[dwi].y, w1v, fmaf(lA[dwi].y, w2v, acc0[0][1]));
                    acc0[0][2] = fmaf(g[dwi].z, w1v, fmaf(lA[dwi].z, w2v, acc0[0][2]));
                    acc0[0][3] = fmaf(g[dwi].w, w1v, fmaf(lA[dwi].w, w2v, acc0[0][3]));
                    acc1[0][0] = fmaf(g[dwi + 1].x, w1v, fmaf(lB[dwi].x, w2v, acc1[0][0]));
                    acc1[0][1] = fmaf(g[dwi + 1].y, w1v, fmaf(lB[dwi].y, w2v, acc1[0][1]));
                    acc1[0][2] = fmaf(g[dwi + 1].z, w1v, fmaf(lB[dwi].z, w2v, acc1[0][2]));
                    acc1[0][3] = fmaf(g[dwi + 1].w, w1v, fmaf(lB[dwi].w, w2v, acc1[0][3]));
                }
            }
        }
        // no loop-end barrier (double-buffered; next post-write barrier suffices)
    }

#pragma unroll
    for (int co = 0; co < CO; ++co) {
        float* op0 = out + ((size_t)co * HW + hw0) * SP + p4;
        float* op1 = op0 + SP;
        float4 r0, r1;
        r0.x = fmaxf(acc0[co][0], 0.0f); r0.y = fmaxf(acc0[co][1], 0.0f);
        r0.z = fmaxf(acc0[co][2], 0.0f); r0.w = fmaxf(acc0[co][3], 0.0f);
        r1.x = fmaxf(acc1[co][0], 0.0f); r1.y = fmaxf(acc1[co][1], 0.0f);
        r1.z = fmaxf(acc1[co][2], 0.0f); r1.w = fmaxf(acc1[co][3], 0.0f);
        *(float4*)op0 = r0;
        *(float4*)op1 = r1;
    }
}

template <int CI, int CO>
__global__ __launch_bounds__(256) void conv4d_pair(
    const float* __restrict__ in0, const float* __restrict__ in1,
    float* __restrict__ out0, float* __restrict__ out1,
    const float* __restrict__ wt,
    const float* __restrict__ bA, const float* __restrict__ bB,
    int branch_base) {
    __shared__ float tile[2][2][SP];   // 16 KB double-buffered pair tiles
    int branch = blockIdx.y + branch_base;
    int bx = blockIdx.x;           // 512 blocks: h in [0,32), w-pair in [0,16)
    int h = bx >> 4;
    int w0 = (bx & 15) << 1;
    if (branch == 0)
        conv_pair_body<CI, CO, false>(in0, out0, wt, bA, bB, tile, h, w0);
    else
        conv_pair_body<CI, CO, true>(in1, out1, wt, bA, bB, tile, h, w0);
}

// ---------------- mm + mask + softmax, s = s1+s2; batch via blockIdx.y ----------------
__global__ void mm_softmax(const float* __restrict__ s1, const float* __restrict__ s2,
                           const float* __restrict__ binv, const int* __restrict__ mask,
                           float* __restrict__ attn) {
    size_t b = blockIdx.y;
    s1 += b * CH1; s2 += b * CH1; binv += b * SP; mask += b * SP; attn += b * CH1;
    __shared__ float red[4];
    int row = blockIdx.x;
    int p4 = threadIdx.x << 2;
    float4 v = *(const float4*)&s1[(size_t)row * SP + p4];
    float4 u = *(const float4*)&s2[(size_t)row * SP + p4];
    v.x += u.x; v.y += u.y; v.z += u.z; v.w += u.w;
    float m = fmaxf(fmaxf(v.x, v.y), fmaxf(v.z, v.w));
    m = block_max(m, red);
    float rinv = 1.0f / (m + EPS);
    float4 bi = *(const float4*)&binv[p4];
    int4 mk = *(const int4*)&mask[p4];
    float lg[4];
    lg[0] = (mk.x != 0) ? MASK_FILL * TEMPF : v.x * v.x * v.x * rinv * bi.x * TEMPF;
    lg[1] = (mk.y != 0) ? MASK_FILL * TEMPF : v.y * v.y * v.y * rinv * bi.y * TEMPF;
    lg[2] = (mk.z != 0) ? MASK_FILL * TEMPF : v.z * v.z * v.z * rinv * bi.z * TEMPF;
    lg[3] = (mk.w != 0) ? MASK_FILL * TEMPF : v.w * v.w * v.w * rinv * bi.w * TEMPF;
    float lm = fmaxf(fmaxf(lg[0], lg[1]), fmaxf(lg[2], lg[3]));
    lm = block_max(lm, red);
    float e[4], ss = 0.0f;
#pragma unroll
    for (int k = 0; k < 4; ++k) {
        e[k] = expf(lg[k] - lm);
        ss += e[k];
    }
    ss = block_sum(ss, red);
    float inv = 1.0f / ss;
    float4 o = {e[0] * inv, e[1] * inv, e[2] * inv, e[3] * inv};
    *(float4*)&attn[(size_t)row * SP + p4] = o;
}

// ---------------- einsum GEMM: out[c,q] = sum_s V[c,s]*A[q,s]; batch via blockIdx.z ----------------
__global__ __launch_bounds__(256) void gemm_vat(const float* __restrict__ V,
                                                const float* __restrict__ A,
                                                float* __restrict__ out) {
    size_t b = blockIdx.z;
    V += b * 256 * 1024; A += b * CH1; out += b * 256 * 1024;
    __shared__ float As[64][36];
    __shared__ float Bs[64][36];
    int c0 = blockIdx.y * 64, q0 = blockIdx.x * 64;
    int tr = threadIdx.x & 15, tc = threadIdx.x >> 4;
    float acc[4][4] = {};
    for (int k0 = 0; k0 < 1024; k0 += 32) {
#pragma unroll
        for (int j = 0; j < 2; ++j) {
            int idx = threadIdx.x + j * 256;
            int row = idx >> 3, c4 = (idx & 7) * 4;
            *(float4*)&As[row][c4] = *(const float4*)&V[(size_t)(c0 + row) * 1024 + k0 + c4];
            *(float4*)&Bs[row][c4] = *(const float4*)&A[(size_t)(q0 + row) * 1024 + k0 + c4];
        }
        __syncthreads();
#pragma unroll
        for (int kk = 0; kk < 8; ++kk) {
            float4 a[4], bb[4];
#pragma unroll
            for (int i = 0; i < 4; ++i) a[i] = *(float4*)&As[tr * 4 + i][kk * 4];
#pragma unroll
            for (int j = 0; j < 4; ++j) bb[j] = *(float4*)&Bs[tc * 4 + j][kk * 4];
#pragma unroll
            for (int i = 0; i < 4; ++i)
#pragma unroll
                for (int j = 0; j < 4; ++j)
                    acc[i][j] += a[i].x * bb[j].x + a[i].y * bb[j].y +
                                 a[i].z * bb[j].z + a[i].w * bb[j].w;
        }
        __syncthreads();
    }
#pragma unroll
    for (int i = 0; i < 4; ++i) {
        float4 o = {acc[i][0], acc[i][1], acc[i][2], acc[i][3]};
        *(float4*)&out[(size_t)(c0 + tr * 4 + i) * 1024 + q0 + tc * 4] = o;
    }
}

extern "C" void kernel_launch(void* const* d_in, const int* in_sizes, int n_in,
                              void* d_out, int out_size, void* d_ws, size_t ws_size,
                              hipStream_t stream) {
    const float* corr = (const float*)d_in[0];
    const float* v = (const float*)d_in[1];
    const int* mask = (const int*)d_in[2];
    const float* l0w1 = (const float*)d_in[3];
    const float* l0b1 = (const float*)d_in[4];
    const float* l0w2 = (const float*)d_in[5];
    const float* l0b2 = (const float*)d_in[6];
    const float* l1w1 = (const float*)d_in[7];
    const float* l1b1 = (const float*)d_in[8];
    const float* l1w2 = (const float*)d_in[9];
    const float* l1b2 = (const float*)d_in[10];
    const float* l2w1 = (const float*)d_in[11];
    const float* l2b1 = (const float*)d_in[12];
    const float* l2w2 = (const float*)d_in[13];
    const float* l2b2 = (const float*)d_in[14];
    float* W = (float*)d_ws;
    float* out = (float*)d_out;
    (void)in_sizes; (void)n_in; (void)out_size;

    const size_t need2 = (4 * CH10 + 12 * CH1 + 2160) * sizeof(float);  // ~218 MB
    const size_t need1 = (4 * CH10 + 2 * CH1 + 2160) * sizeof(float);   // ~176 MB
    dim3 gp2(512, 2), gp1(512, 1);

    if (ws_size >= need2) {
        // -------- fully batched small kernels, branch-parallel convs --------
        float* P1 = W;
        float* Q1 = P1 + CH10;
        float* P2 = Q1 + CH10;
        float* Q2 = P2 + CH10;
        float* C1 = Q2 + CH10;            // 4 x CH1
        float* S = C1 + 4 * CH1;          // 8 x CH1: S1[b]=S+b*CH1, S2[b]=S+(4+b)*CH1
        float* wt = S + 8 * CH1;
        float* PART = P2;                 // alias: P2 dead during stage1/stage2
        float* MB0 = P2 + 4 * 256 * SP;
        float* MB1 = MB0 + 4 * SP;
        float* ATTN = P1;                 // alias: P1 dead during stage2

        wt_prep<<<1, 256, 0, stream>>>(l0w1, l0w2, l1w1, l1w2, l2w1, l2w2, wt);

        // stage 1, all batches
        colmax_part<false><<<dim3(256, BN), 256, 0, stream>>>(corr, corr, PART);
        colmax_comb<<<dim3(4, BN), 256, 0, stream>>>(PART, MB0);
        mm_rows<<<dim3(HW, BN), 256, 0, stream>>>(corr, MB0, C1);

        // convs per batch (shared P/Q), both branches concurrent
        for (int b = 0; b < BN; ++b) {
            float* C1b = C1 + (size_t)b * CH1;
            float* S1b = S + (size_t)b * CH1;
            float* S2b = S + (size_t)(4 + b) * CH1;
            conv4d_pair<1, 10><<<gp2, 256, 0, stream>>>(C1b, C1b, P1, P2, wt, l0b1, l0b2, 0);
            conv4d_pair<10, 10><<<gp2, 256, 0, stream>>>(P1, P2, Q1, Q2, wt + 180, l1b1, l1b2, 0);
            conv4d_pair<10, 1><<<gp2, 256, 0, stream>>>(Q1, Q2, S1b, S2b, wt + 1980, l2b1, l2b2, 0);
        }

        // stage 2, all batches
        colmax_part<true><<<dim3(256, BN), 256, 0, stream>>>(S, S + 4 * CH1, PART);
        colmax_comb<<<dim3(4, BN), 256, 0, stream>>>(PART, MB1);
        mm_softmax<<<dim3(HW, BN), 256, 0, stream>>>(S, S + 4 * CH1, MB1, mask, ATTN);
        gemm_vat<<<dim3(16, 4, BN), 256, 0, stream>>>(v, ATTN, out);
    } else {
        bool par = ws_size >= need1;
        float *P1, *Q1, *P2, *Q2, *C1, *S1, *S2, *wt;
        if (par) {
            P1 = W; Q1 = P1 + CH10; P2 = Q1 + CH10; Q2 = P2 + CH10;
            S1 = Q2 + CH10; S2 = S1 + CH1; wt = S2 + CH1;
            C1 = Q1;
        } else {
            P1 = W; Q1 = P1 + CH10; C1 = Q1 + CH10; S1 = C1 + CH1; S2 = S1 + CH1;
            wt = S2 + CH1;
            P2 = P1; Q2 = Q1;
        }
        float* PART = P1;
        float* MB0 = P1 + 256 * SP;
        float* MB1 = MB0 + SP;
        float* ATTN = P1 + 512 * SP;

        wt_prep<<<1, 256, 0, stream>>>(l0w1, l0w2, l1w1, l1w2, l2w1, l2w2, wt);

        for (int b = 0; b < BN; ++b) {
            const float* corr_b = corr + (size_t)b * CH1;
            const float* v_b = v + (size_t)b * 256 * 1024;
            const int* mask_b = mask + (size_t)b * SP;
            float* out_b = out + (size_t)b * 256 * 1024;

            colmax_part<false><<<dim3(256, 1), 256, 0, stream>>>(corr_b, corr_b, PART);
            colmax_comb<<<dim3(4, 1), 256, 0, stream>>>(PART, MB0);
            mm_rows<<<dim3(HW, 1), 256, 0, stream>>>(corr_b, MB0, C1);

            if (par) {
                conv4d_pair<1, 10><<<gp2, 256, 0, stream>>>(C1, C1, P1, P2, wt, l0b1, l0b2, 0);
                conv4d_pair<10, 10><<<gp2, 256, 0, stream>>>(P1, P2, Q1, Q2, wt + 180, l1b1, l1b2, 0);
                conv4d_pair<10, 1><<<gp2, 256, 0, stream>>>(Q1, Q2, S1, S2, wt + 1980, l2b1, l2b2, 0);
            } else {
                conv4d_pair<1, 10><<<gp1, 256, 0, stream>>>(C1, C1, P1, P1, wt, l0b1, l0b2, 0);
                conv4d_pair<10, 10><<<gp1, 256, 0, stream>>>(P1, P1, Q1, Q1, wt + 180, l1b1, l1b2, 0);
                conv4d_pair<10, 1><<<gp1, 256, 0, stream>>>(Q1, Q1, S1, S1, wt + 1980, l2b1, l2b2, 0);
                conv4d_pair<1, 10><<<gp1, 256, 0, stream>>>(C1, C1, P1, P1, wt, l0b1, l0b2, 1);
                conv4d_pair<10, 10><<<gp1, 256, 0, stream>>>(P1, P1, Q1, Q1, wt + 180, l1b1, l1b2, 1);
                conv4d_pair<10, 1><<<gp1, 256, 0, stream>>>(Q1, Q1, S2, S2, wt + 1980, l2b1, l2b2, 1);
            }

            colmax_part<true><<<dim3(256, 1), 256, 0, stream>>>(S1, S2, PART);
            colmax_comb<<<dim3(4, 1), 256, 0, stream>>>(PART, MB1);
            mm_softmax<<<dim3(HW, 1), 256, 0, stream>>>(S1, S2, MB1, mask_b, ATTN);
            gemm_vat<<<dim3(16, 4, 1), 256, 0, stream>>>(v_b, ATTN, out_b);
        }
    }
}